// Round 23
// baseline (292.534 us; speedup 1.0000x reference)
//
#include <hip/hip_runtime.h>

// Net_17532056502451 round 23: conv with 4 positions per lane (1 readlane
// feeds 4 FMAs), 8 k-eighths, 512-thr blocks, launch_bounds(512,4).
// Per-acc j-order unchanged. k_fuse M-GEMV unrolled. Rest = r22.
//
// ws layout (floats):
#define WS_XRES   0
#define WS_YRES   81920
#define WS_WT     163840   // Wt[c*512+f] = W_enc[f*160+c]
#define WS_MT     245760   // Mt[c*160+o] = sum_f Wsrc[o,f] Wenc[f,c]  (160x160)
#define WS_D0     271360   // d0[o]
#define WS_G      327680   // G padded [160][164]
#define WS_U      353920   // u[160]
#define WS_BB     354080
#define WS_K      354081
#define WS_LOSS   354082   // 5 raw sq-sums (atomic)
#define WS_YA     354088   // [1024][88]   (fuse-local layout)
#define WS_XELE   444200   // [1024][80]
#define WS_EN     526120   // [1024][84]
#define WS_YAT    612160   // [80][1024]   (conv layout, transposed)

#define GPITCH 164

__device__ __forceinline__ float rl(float v, int l) {
    return __int_as_float(__builtin_amdgcn_readlane(__float_as_int(v), l));
}

__global__ void k_init(const float* __restrict__ x, const float* __restrict__ y,
                       const float* __restrict__ Wenc, float* __restrict__ ws) {
    int i = blockIdx.x * 256 + threadIdx.x;   // covers 81920
    ws[WS_XRES + i] = x[i];
    ws[WS_YRES + i] = y[i];
    int f = i / 160, c = i - f * 160;
    ws[WS_WT + c * 512 + f] = Wenc[i];
    if (i == 0) {
        ws[WS_K] = 0.0f;
        for (int t = 0; t < 5; ++t) ws[WS_LOSS + t] = 0.0f;
    }
}

__device__ __forceinline__ float wave_sum(float v) {
    for (int d = 32; d > 0; d >>= 1) v += __shfl_down(v, d);
    return __shfl(v, 0);
}
__device__ __forceinline__ float wave_max(float v) {
    for (int d = 32; d > 0; d >>= 1) v = fmaxf(v, __shfl_down(v, d));
    return __shfl(v, 0);
}
__device__ __forceinline__ int wave_argmax(float v, int i) {
    for (int d = 32; d > 0; d >>= 1) {
        float v2 = __shfl_down(v, d);
        int   i2 = __shfl_down(i, d);
        if (v2 > v || (v2 == v && i2 < i)) { v = v2; i = i2; }
    }
    return __shfl(i, 0);
}

__global__ __launch_bounds__(256)
void k_cnt(const float* __restrict__ y, float* __restrict__ ws) {
    __shared__ int red[256];
    int tid = threadIdx.x;
    int i = blockIdx.x * 256 + tid;
    red[tid] = (y[i] != 0.0f) ? 1 : 0;
    __syncthreads();
    for (int s = 128; s > 0; s >>= 1) {
        if (tid < s) red[tid] += red[tid + s];
        __syncthreads();
    }
    if (tid == 0) atomicAdd(&ws[WS_K], (float)red[0]);
}

// G rows (b<160) / u+bb (b==160): per-thread column, coalesced Wenc reads.
__global__ __launch_bounds__(256)
void k_pre(const float* __restrict__ Wenc, const float* __restrict__ benc,
           float* __restrict__ ws) {
    const int b = blockIdx.x, tid = threadIdx.x;
    __shared__ float wr[512];
    if (b < 160) {
        wr[tid] = ws[WS_WT + b * 512 + tid];
        wr[tid + 256] = ws[WS_WT + b * 512 + 256 + tid];
        __syncthreads();
        if (tid < 160) {
            const float* Wc = Wenc + tid;
            float a0 = 0.f, a1 = 0.f, a2 = 0.f, a3 = 0.f;
            for (int f = 0; f < 512; f += 4) {
                a0 = fmaf(wr[f],     Wc[f * 160],       a0);
                a1 = fmaf(wr[f + 1], Wc[(f + 1) * 160], a1);
                a2 = fmaf(wr[f + 2], Wc[(f + 2) * 160], a2);
                a3 = fmaf(wr[f + 3], Wc[(f + 3) * 160], a3);
            }
            ws[WS_G + b * GPITCH + tid] = (a0 + a1) + (a2 + a3);
        }
    } else {
        wr[tid] = benc[tid];
        wr[tid + 256] = benc[tid + 256];
        __syncthreads();
        if (tid < 160) {
            const float* Wc = Wenc + tid;
            float a0 = 0.f, a1 = 0.f, a2 = 0.f, a3 = 0.f;
            for (int f = 0; f < 512; f += 4) {
                a0 = fmaf(wr[f],     Wc[f * 160],       a0);
                a1 = fmaf(wr[f + 1], Wc[(f + 1) * 160], a1);
                a2 = fmaf(wr[f + 2], Wc[(f + 2) * 160], a2);
                a3 = fmaf(wr[f + 3], Wc[(f + 3) * 160], a3);
            }
            ws[WS_U + tid] = (a0 + a1) + (a2 + a3);
        }
        if (tid < 64) {
            float a = 0.0f;
#pragma unroll
            for (int jj = 0; jj < 8; ++jj) {
                float bv = wr[tid + 64 * jj];
                a = fmaf(bv, bv, a);
            }
            a = wave_sum(a);
            if (tid == 0) ws[WS_BB] = a;
        }
    }
}

// Mt[c][o] = sum_f Wsrc[o,f] Wenc[f,c]; d0[o] = sum_f Wsrc[o,f] benc[f]
__global__ __launch_bounds__(256)
void k_preM(const float* __restrict__ Wenc, const float* __restrict__ benc,
            const float* __restrict__ Wsrc, float* __restrict__ ws) {
    const int o = blockIdx.x, tid = threadIdx.x;
    __shared__ float wr[512];
    wr[tid] = Wsrc[o * 512 + tid];
    wr[tid + 256] = Wsrc[o * 512 + 256 + tid];
    __syncthreads();
    if (tid < 160) {
        const float* Wc = Wenc + tid;
        float a0 = 0.f, a1 = 0.f, a2 = 0.f, a3 = 0.f;
        for (int f = 0; f < 512; f += 4) {
            a0 = fmaf(wr[f],     Wc[f * 160],       a0);
            a1 = fmaf(wr[f + 1], Wc[(f + 1) * 160], a1);
            a2 = fmaf(wr[f + 2], Wc[(f + 2) * 160], a2);
            a3 = fmaf(wr[f + 3], Wc[(f + 3) * 160], a3);
        }
        ws[WS_MT + tid * 160 + o] = (a0 + a1) + (a2 + a3);
    }
    if (tid < 64) {
        float a = 0.0f;
#pragma unroll
        for (int jj = 0; jj < 8; ++jj)
            a = fmaf(wr[tid + 64 * jj], benc[tid + 64 * jj], a);
        a = wave_sum(a);
        if (tid == 0) ws[WS_D0 + o] = a;
    }
}

// ---------------- k_sel: initial selector + softmax per position ----------------
__global__ __launch_bounds__(128)
void k_sel(float* __restrict__ ws) {
    const int p = blockIdx.x, tid = threadIdx.x, lane = tid & 63;
    const int base = p * 80;
    __shared__ float xr[80], yr[80], simS[160], ya[88];
    __shared__ float s_ny2;

    if (tid < 80) { xr[tid] = ws[WS_XRES + base + tid]; yr[tid] = ws[WS_YRES + base + tid]; }
    __syncthreads();

    if (tid < 64) {
        float a = yr[lane];
        float v = a * a;
        if (lane < 16) { float u = yr[64 + lane]; v = fmaf(u, u, v); }
        v = wave_sum(v);
        if (lane == 0) s_ny2 = v;
    }
    __syncthreads();

    for (int s = tid; s < 159; s += 128) {
        int ilo = (s - 79 > 0) ? s - 79 : 0;
        int ihi = (s < 79) ? s : 79;
        float dot = 0.0f, nx2 = 0.0f;
        for (int i = ilo; i <= ihi; ++i) {
            float xv = xr[i];
            dot = fmaf(xv, yr[i - s + 79], dot);
            nx2 = fmaf(xv, xv, nx2);
        }
        float denom = sqrtf(nx2) * sqrtf(s_ny2);
        simS[s] = (denom == 0.0f) ? 0.0f : dot / denom;
    }
    __syncthreads();

    if (tid < 64) {
        int theta;
        {
            float v = simS[lane]; int i = lane;
            { float v2 = simS[lane + 64]; int i2 = lane + 64;
              if (v2 > v || (v2 == v && i2 < i)) { v = v2; i = i2; } }
            if (lane < 31) {
                float v2 = simS[lane + 128]; int i2 = lane + 128;
                if (v2 > v || (v2 == v && i2 < i)) { v = v2; i = i2; }
            }
            theta = wave_argmax(v, i);
        }
        int t0 = lane, t1 = lane + 64;
        int ix0 = theta + t0 - 79;
        float ya0 = (ix0 >= 0 && ix0 < 80) ? xr[ix0] : 0.0f;
        float z0 = ya0 * yr[t0] / 0.7f;
        float ya1 = 0.0f, z1 = -INFINITY;
        if (t1 < 80) {
            int ix1 = theta + t1 - 79;
            ya1 = (ix1 >= 0 && ix1 < 80) ? xr[ix1] : 0.0f;
            z1 = ya1 * yr[t1] / 0.7f;
        }
        float m = wave_max(fmaxf(z0, z1));
        float e0 = expf(z0 - m);
        float e1 = (t1 < 80) ? expf(z1 - m) : 0.0f;
        float S = wave_sum(e0 + e1);
        float v0 = ya0 * (e0 / S);
        ya[t0] = v0;
        ws[WS_YA + p * 88 + t0] = v0;
        ws[WS_YAT + t0 * 1024 + p] = v0;
        if (t1 < 80) {
            float v1 = ya1 * (e1 / S);
            ya[t1] = v1;
            ws[WS_YA + p * 88 + t1] = v1;
            ws[WS_YAT + t1 * 1024 + p] = v1;
        }
        if (lane < 8) ws[WS_YA + p * 88 + 80 + lane] = 0.0f;
        int k0 = 79 - theta + t0;
        ws[WS_XELE + base + t0] = (k0 >= 0 && k0 < 80) ? ya[k0] : 0.0f;
        if (t1 < 80) {
            int k1 = 79 - theta + t1;
            ws[WS_XELE + base + t1] = (k1 >= 0 && k1 < 80) ? ya[k1] : 0.0f;
        }
    }
}

// ---------------- k_conv: 4 positions/lane, 8 k-eighths, full-lane j-tiles ----------------
__global__ __launch_bounds__(512, 4)
void k_conv(const float* __restrict__ G, const float* __restrict__ uvec,
            const float* __restrict__ yat, const float* __restrict__ bbp,
            float* __restrict__ en) {
    const int bid = blockIdx.x;       // 81 * 4
    const int s   = bid >> 2;
    const int pg  = bid & 3;
    const int c0  = 80 - s;
    const int tid = threadIdx.x;
    const int pl  = tid & 63;         // lane
    const int wv  = tid >> 6;         // 0..7 : k-eighth
    const int p0  = pg * 256 + pl;

    __shared__ float e_l[4][512];

    const int r0 = wv * 10;
    const float* Grow = G + (c0 + r0) * GPITCH + c0;

    float a0[10], a1[10], a2[10], a3[10];
#pragma unroll
    for (int rr = 0; rr < 10; ++rr) { a0[rr]=0.f; a1[rr]=0.f; a2[rr]=0.f; a3[rr]=0.f; }

    // ---- j-tile 0: j = 0..63 (g lane pl carries col c0+pl) ----
    {
        float g[10];
#pragma unroll
        for (int rr = 0; rr < 10; ++rr) g[rr] = Grow[rr * GPITCH + pl];
#pragma unroll
        for (int rr = 0; rr < 10; ++rr) asm volatile("" : "+v"(g[rr]));
#pragma unroll 4
        for (int j = 0; j < 64; ++j) {
            const float y0 = yat[j * 1024 + p0];
            const float y1 = yat[j * 1024 + p0 + 64];
            const float y2 = yat[j * 1024 + p0 + 128];
            const float y3 = yat[j * 1024 + p0 + 192];
#pragma unroll
            for (int rr = 0; rr < 10; ++rr) {
                const float gv = rl(g[rr], j);
                a0[rr] = fmaf(gv, y0, a0[rr]);
                a1[rr] = fmaf(gv, y1, a1[rr]);
                a2[rr] = fmaf(gv, y2, a2[rr]);
                a3[rr] = fmaf(gv, y3, a3[rr]);
            }
        }
    }
    // ---- j-tile 1: j = 64..79 (g lane pl carries col c0+64+pl; lanes>=16 unused) ----
    {
        float g[10];
#pragma unroll
        for (int rr = 0; rr < 10; ++rr) g[rr] = Grow[rr * GPITCH + 64 + pl];
#pragma unroll
        for (int rr = 0; rr < 10; ++rr) asm volatile("" : "+v"(g[rr]));
#pragma unroll 4
        for (int j = 0; j < 16; ++j) {
            const float y0 = yat[(64 + j) * 1024 + p0];
            const float y1 = yat[(64 + j) * 1024 + p0 + 64];
            const float y2 = yat[(64 + j) * 1024 + p0 + 128];
            const float y3 = yat[(64 + j) * 1024 + p0 + 192];
#pragma unroll
            for (int rr = 0; rr < 10; ++rr) {
                const float gv = rl(g[rr], j);
                a0[rr] = fmaf(gv, y0, a0[rr]);
                a1[rr] = fmaf(gv, y1, a1[rr]);
                a2[rr] = fmaf(gv, y2, a2[rr]);
                a3[rr] = fmaf(gv, y3, a3[rr]);
            }
        }
    }

    // epilogue: e = sum_rr y[r0+rr] * (v_k + 2 u_k), rr ascending, per position
    const float* up = uvec + c0 + r0;
    float e0 = 0.f, e1 = 0.f, e2 = 0.f, e3 = 0.f;
#pragma unroll
    for (int rr = 0; rr < 10; ++rr) {
        const float t = 2.0f * up[rr];
        const int row = (r0 + rr) * 1024 + p0;
        e0 = fmaf(yat[row],       a0[rr] + t, e0);
        e1 = fmaf(yat[row + 64],  a1[rr] + t, e1);
        e2 = fmaf(yat[row + 128], a2[rr] + t, e2);
        e3 = fmaf(yat[row + 192], a3[rr] + t, e3);
    }
    e_l[0][tid] = e0;
    e_l[1][tid] = e1;
    e_l[2][tid] = e2;
    e_l[3][tid] = e3;
    __syncthreads();
    if (tid < 256) {
        const int ps = tid >> 6;          // position sub-group 0..3
        const int l2 = tid & 63;
        const float* el = e_l[ps];
        float s01 = (el[l2] + el[l2 + 64]) + (el[l2 + 128] + el[l2 + 192]);
        float s23 = (el[l2 + 256] + el[l2 + 320]) + (el[l2 + 384] + el[l2 + 448]);
        en[(pg * 256 + ps * 64 + l2) * 84 + s] = bbp[0] + (s01 + s23);
    }
}

// -------- k_fuse: argmax + halved M-GEMV + loss + residuals + next-iter sel --------
__global__ __launch_bounds__(128)
void k_fuse(const float* __restrict__ yorig, const float* __restrict__ bsrc,
            float* __restrict__ ws, int it) {
    const int p = blockIdx.x, tid = threadIdx.x;
    const int lane = tid & 63;
    const int base = p * 80;

    __shared__ float ya_l[84], yr_l[80], xr_l[80], xele_l[80];
    __shared__ float xext80[80];
    __shared__ float yr2[80], xr2[80], simS[160], ya_n[88];
    __shared__ float s_ny2;
    __shared__ int s_hind;

    if (tid < 84) ya_l[tid] = ws[WS_YA + p * 88 + tid];
    if (tid < 80) {
        yr_l[tid]   = ws[WS_YRES + base + tid];
        xr_l[tid]   = ws[WS_XRES + base + tid];
        xele_l[tid] = ws[WS_XELE + base + tid];
    }
    __syncthreads();

    if (tid < 64) {
        float v = ws[WS_EN + p * 84 + lane]; int i = lane;
        if (lane < 17) {
            float v2 = ws[WS_EN + p * 84 + lane + 64]; int i2 = lane + 64;
            if (v2 > v || (v2 == v && i2 < i)) { v = v2; i = i2; }
        }
        int hind = wave_argmax(v, i);
        if (lane == 0) s_hind = hind;
    }
    __syncthreads();
    const int hd = s_hind;
    const int cb = 80 - hd;

    // xext80[t] = xext[cb+t] = bsrc[o] + d0[o] + sum_k ya[k]*Mt[(cb+k)*160+o]
    if (tid < 80) {
        const int o = cb + tid;
        const float* M = ws + WS_MT + cb * 160 + o;
        float a0 = bsrc[o] + ws[WS_D0 + o], a1 = 0.f, a2 = 0.f, a3 = 0.f;
#pragma unroll
        for (int k = 0; k < 80; k += 4) {
            a0 = fmaf(ya_l[k],     M[k * 160],       a0);
            a1 = fmaf(ya_l[k + 1], M[(k + 1) * 160], a1);
            a2 = fmaf(ya_l[k + 2], M[(k + 2) * 160], a2);
            a3 = fmaf(ya_l[k + 3], M[(k + 3) * 160], a3);
        }
        xext80[tid] = (a0 + a1) + (a2 + a3);
    }
    __syncthreads();

    if (tid < 64) {
        int t0 = lane, t1 = lane + 64;
        float sq;
        {
            float yele = xext80[t0];
            float yv = yr_l[t0];
            float keep = (yorig[base + t0] != 0.0f) ? 1.0f : 0.0f;
            float d = yele - yv;
            sq = d * d * keep;
            float ynew = yv - yele;
            float xnew = xr_l[t0] - xele_l[t0];
            yr2[t0] = ynew; xr2[t0] = xnew;
            ws[WS_YRES + base + t0] = ynew;
            ws[WS_XRES + base + t0] = xnew;
        }
        if (t1 < 80) {
            float yele = xext80[t1];
            float yv = yr_l[t1];
            float keep = (yorig[base + t1] != 0.0f) ? 1.0f : 0.0f;
            float d = yele - yv;
            sq = fmaf(d * keep, d, sq);
            float ynew = yv - yele;
            float xnew = xr_l[t1] - xele_l[t1];
            yr2[t1] = ynew; xr2[t1] = xnew;
            ws[WS_YRES + base + t1] = ynew;
            ws[WS_XRES + base + t1] = xnew;
        }
        sq = wave_sum(sq);
        if (lane == 0) atomicAdd(&ws[WS_LOSS + it], sq);
    }
    if (it == 4) return;
    __syncthreads();

    // ---- fused selector for next iteration ----
    if (tid < 64) {
        float a = yr2[lane];
        float v = a * a;
        if (lane < 16) { float u = yr2[64 + lane]; v = fmaf(u, u, v); }
        v = wave_sum(v);
        if (lane == 0) s_ny2 = v;
    }
    __syncthreads();

    for (int s = tid; s < 159; s += 128) {
        int ilo = (s - 79 > 0) ? s - 79 : 0;
        int ihi = (s < 79) ? s : 79;
        float dot = 0.0f, nx2 = 0.0f;
        for (int i = ilo; i <= ihi; ++i) {
            float xv = xr2[i];
            dot = fmaf(xv, yr2[i - s + 79], dot);
            nx2 = fmaf(xv, xv, nx2);
        }
        float denom = sqrtf(nx2) * sqrtf(s_ny2);
        simS[s] = (denom == 0.0f) ? 0.0f : dot / denom;
    }
    __syncthreads();

    if (tid < 64) {
        int theta;
        {
            float v = simS[lane]; int i = lane;
            { float v2 = simS[lane + 64]; int i2 = lane + 64;
              if (v2 > v || (v2 == v && i2 < i)) { v = v2; i = i2; } }
            if (lane < 31) {
                float v2 = simS[lane + 128]; int i2 = lane + 128;
                if (v2 > v || (v2 == v && i2 < i)) { v = v2; i = i2; }
            }
            theta = wave_argmax(v, i);
        }
        int t0 = lane, t1 = lane + 64;
        int ix0 = theta + t0 - 79;
        float ya0 = (ix0 >= 0 && ix0 < 80) ? xr2[ix0] : 0.0f;
        float z0 = ya0 * yr2[t0] / 0.7f;
        float ya1 = 0.0f, z1 = -INFINITY;
        if (t1 < 80) {
            int ix1 = theta + t1 - 79;
            ya1 = (ix1 >= 0 && ix1 < 80) ? xr2[ix1] : 0.0f;
            z1 = ya1 * yr2[t1] / 0.7f;
        }
        float m = wave_max(fmaxf(z0, z1));
        float e0 = expf(z0 - m);
        float e1 = (t1 < 80) ? expf(z1 - m) : 0.0f;
        float S = wave_sum(e0 + e1);
        float v0 = ya0 * (e0 / S);
        ya_n[t0] = v0;
        ws[WS_YA + p * 88 + t0] = v0;
        ws[WS_YAT + t0 * 1024 + p] = v0;
        if (t1 < 80) {
            float v1 = ya1 * (e1 / S);
            ya_n[t1] = v1;
            ws[WS_YA + p * 88 + t1] = v1;
            ws[WS_YAT + t1 * 1024 + p] = v1;
        }
        if (lane < 8) ws[WS_YA + p * 88 + 80 + lane] = 0.0f;
        int k0 = 79 - theta + t0;
        ws[WS_XELE + base + t0] = (k0 >= 0 && k0 < 80) ? ya_n[k0] : 0.0f;
        if (t1 < 80) {
            int k1 = 79 - theta + t1;
            ws[WS_XELE + base + t1] = (k1 >= 0 && k1 < 80) ? ya_n[k1] : 0.0f;
        }
    }
}

__global__ void k_final(const float* __restrict__ ws, float* __restrict__ out) {
    float K = ws[WS_K];
    if (K < 1.0f) K = 1.0f;
    out[0] = (ws[WS_LOSS] + ws[WS_LOSS + 1] + ws[WS_LOSS + 2] +
              ws[WS_LOSS + 3] + ws[WS_LOSS + 4]) / (K * 5.0f);
}

extern "C" void kernel_launch(void* const* d_in, const int* in_sizes, int n_in,
                              void* d_out, int out_size, void* d_ws, size_t ws_size,
                              hipStream_t stream) {
    const float* x    = (const float*)d_in[0];
    const float* y    = (const float*)d_in[1];
    const float* Wenc = (const float*)d_in[2];
    const float* benc = (const float*)d_in[3];
    const float* Wsrc = (const float*)d_in[4];
    const float* bsrc = (const float*)d_in[5];
    float* ws  = (float*)d_ws;
    float* out = (float*)d_out;

    k_init<<<320, 256, 0, stream>>>(x, y, Wenc, ws);
    k_cnt<<<320, 256, 0, stream>>>(y, ws);
    k_pre<<<161, 256, 0, stream>>>(Wenc, benc, ws);
    k_preM<<<160, 256, 0, stream>>>(Wenc, benc, Wsrc, ws);
    k_sel<<<1024, 128, 0, stream>>>(ws);
    for (int it = 0; it < 5; ++it) {
        k_conv<<<81 * 4, 512, 0, stream>>>(ws + WS_G, ws + WS_U, ws + WS_YAT,
                                           ws + WS_BB, ws + WS_EN);
        k_fuse<<<1024, 128, 0, stream>>>(y, bsrc, ws, it);
    }
    k_final<<<1, 1, 0, stream>>>(ws, out);
}

// Round 24
// 274.445 us; speedup vs baseline: 1.0659x; 1.0659x over previous
//
#include <hip/hip_runtime.h>

// Net_17532056502451 round 24: restore round-22 best (273.8 us) verbatim.
// conv: 2 positions per lane — each readlane broadcast feeds 2 FMAs.
//
// ws layout (floats):
#define WS_XRES   0
#define WS_YRES   81920
#define WS_WT     163840   // Wt[c*512+f] = W_enc[f*160+c]
#define WS_MT     245760   // Mt[c*160+o] = sum_f Wsrc[o,f] Wenc[f,c]  (160x160)
#define WS_D0     271360   // d0[o]
#define WS_G      327680   // G padded [160][164]
#define WS_U      353920   // u[160]
#define WS_BB     354080
#define WS_K      354081
#define WS_LOSS   354082   // 5 raw sq-sums (atomic)
#define WS_YA     354088   // [1024][88]   (fuse-local layout)
#define WS_XELE   444200   // [1024][80]
#define WS_EN     526120   // [1024][84]
#define WS_YAT    612160   // [80][1024]   (conv layout, transposed)

#define GPITCH 164

__device__ __forceinline__ float rl(float v, int l) {
    return __int_as_float(__builtin_amdgcn_readlane(__float_as_int(v), l));
}

__global__ void k_init(const float* __restrict__ x, const float* __restrict__ y,
                       const float* __restrict__ Wenc, float* __restrict__ ws) {
    int i = blockIdx.x * 256 + threadIdx.x;   // covers 81920
    ws[WS_XRES + i] = x[i];
    ws[WS_YRES + i] = y[i];
    int f = i / 160, c = i - f * 160;
    ws[WS_WT + c * 512 + f] = Wenc[i];
    if (i == 0) {
        ws[WS_K] = 0.0f;
        for (int t = 0; t < 5; ++t) ws[WS_LOSS + t] = 0.0f;
    }
}

__device__ __forceinline__ float wave_sum(float v) {
    for (int d = 32; d > 0; d >>= 1) v += __shfl_down(v, d);
    return __shfl(v, 0);
}
__device__ __forceinline__ float wave_max(float v) {
    for (int d = 32; d > 0; d >>= 1) v = fmaxf(v, __shfl_down(v, d));
    return __shfl(v, 0);
}
__device__ __forceinline__ int wave_argmax(float v, int i) {
    for (int d = 32; d > 0; d >>= 1) {
        float v2 = __shfl_down(v, d);
        int   i2 = __shfl_down(i, d);
        if (v2 > v || (v2 == v && i2 < i)) { v = v2; i = i2; }
    }
    return __shfl(i, 0);
}

__global__ __launch_bounds__(256)
void k_cnt(const float* __restrict__ y, float* __restrict__ ws) {
    __shared__ int red[256];
    int tid = threadIdx.x;
    int i = blockIdx.x * 256 + tid;
    red[tid] = (y[i] != 0.0f) ? 1 : 0;
    __syncthreads();
    for (int s = 128; s > 0; s >>= 1) {
        if (tid < s) red[tid] += red[tid + s];
        __syncthreads();
    }
    if (tid == 0) atomicAdd(&ws[WS_K], (float)red[0]);
}

// G rows (b<160) / u+bb (b==160): per-thread column, coalesced Wenc reads.
__global__ __launch_bounds__(256)
void k_pre(const float* __restrict__ Wenc, const float* __restrict__ benc,
           float* __restrict__ ws) {
    const int b = blockIdx.x, tid = threadIdx.x;
    __shared__ float wr[512];
    if (b < 160) {
        wr[tid] = ws[WS_WT + b * 512 + tid];
        wr[tid + 256] = ws[WS_WT + b * 512 + 256 + tid];
        __syncthreads();
        if (tid < 160) {
            const float* Wc = Wenc + tid;
            float a0 = 0.f, a1 = 0.f, a2 = 0.f, a3 = 0.f;
            for (int f = 0; f < 512; f += 4) {
                a0 = fmaf(wr[f],     Wc[f * 160],       a0);
                a1 = fmaf(wr[f + 1], Wc[(f + 1) * 160], a1);
                a2 = fmaf(wr[f + 2], Wc[(f + 2) * 160], a2);
                a3 = fmaf(wr[f + 3], Wc[(f + 3) * 160], a3);
            }
            ws[WS_G + b * GPITCH + tid] = (a0 + a1) + (a2 + a3);
        }
    } else {
        wr[tid] = benc[tid];
        wr[tid + 256] = benc[tid + 256];
        __syncthreads();
        if (tid < 160) {
            const float* Wc = Wenc + tid;
            float a0 = 0.f, a1 = 0.f, a2 = 0.f, a3 = 0.f;
            for (int f = 0; f < 512; f += 4) {
                a0 = fmaf(wr[f],     Wc[f * 160],       a0);
                a1 = fmaf(wr[f + 1], Wc[(f + 1) * 160], a1);
                a2 = fmaf(wr[f + 2], Wc[(f + 2) * 160], a2);
                a3 = fmaf(wr[f + 3], Wc[(f + 3) * 160], a3);
            }
            ws[WS_U + tid] = (a0 + a1) + (a2 + a3);
        }
        if (tid < 64) {
            float a = 0.0f;
#pragma unroll
            for (int jj = 0; jj < 8; ++jj) {
                float bv = wr[tid + 64 * jj];
                a = fmaf(bv, bv, a);
            }
            a = wave_sum(a);
            if (tid == 0) ws[WS_BB] = a;
        }
    }
}

// Mt[c][o] = sum_f Wsrc[o,f] Wenc[f,c]; d0[o] = sum_f Wsrc[o,f] benc[f]
__global__ __launch_bounds__(256)
void k_preM(const float* __restrict__ Wenc, const float* __restrict__ benc,
            const float* __restrict__ Wsrc, float* __restrict__ ws) {
    const int o = blockIdx.x, tid = threadIdx.x;
    __shared__ float wr[512];
    wr[tid] = Wsrc[o * 512 + tid];
    wr[tid + 256] = Wsrc[o * 512 + 256 + tid];
    __syncthreads();
    if (tid < 160) {
        const float* Wc = Wenc + tid;
        float a0 = 0.f, a1 = 0.f, a2 = 0.f, a3 = 0.f;
        for (int f = 0; f < 512; f += 4) {
            a0 = fmaf(wr[f],     Wc[f * 160],       a0);
            a1 = fmaf(wr[f + 1], Wc[(f + 1) * 160], a1);
            a2 = fmaf(wr[f + 2], Wc[(f + 2) * 160], a2);
            a3 = fmaf(wr[f + 3], Wc[(f + 3) * 160], a3);
        }
        ws[WS_MT + tid * 160 + o] = (a0 + a1) + (a2 + a3);
    }
    if (tid < 64) {
        float a = 0.0f;
#pragma unroll
        for (int jj = 0; jj < 8; ++jj)
            a = fmaf(wr[tid + 64 * jj], benc[tid + 64 * jj], a);
        a = wave_sum(a);
        if (tid == 0) ws[WS_D0 + o] = a;
    }
}

// ---------------- k_sel: initial selector + softmax per position ----------------
__global__ __launch_bounds__(128)
void k_sel(float* __restrict__ ws) {
    const int p = blockIdx.x, tid = threadIdx.x, lane = tid & 63;
    const int base = p * 80;
    __shared__ float xr[80], yr[80], simS[160], ya[88];
    __shared__ float s_ny2;

    if (tid < 80) { xr[tid] = ws[WS_XRES + base + tid]; yr[tid] = ws[WS_YRES + base + tid]; }
    __syncthreads();

    if (tid < 64) {
        float a = yr[lane];
        float v = a * a;
        if (lane < 16) { float u = yr[64 + lane]; v = fmaf(u, u, v); }
        v = wave_sum(v);
        if (lane == 0) s_ny2 = v;
    }
    __syncthreads();

    for (int s = tid; s < 159; s += 128) {
        int ilo = (s - 79 > 0) ? s - 79 : 0;
        int ihi = (s < 79) ? s : 79;
        float dot = 0.0f, nx2 = 0.0f;
        for (int i = ilo; i <= ihi; ++i) {
            float xv = xr[i];
            dot = fmaf(xv, yr[i - s + 79], dot);
            nx2 = fmaf(xv, xv, nx2);
        }
        float denom = sqrtf(nx2) * sqrtf(s_ny2);
        simS[s] = (denom == 0.0f) ? 0.0f : dot / denom;
    }
    __syncthreads();

    if (tid < 64) {
        int theta;
        {
            float v = simS[lane]; int i = lane;
            { float v2 = simS[lane + 64]; int i2 = lane + 64;
              if (v2 > v || (v2 == v && i2 < i)) { v = v2; i = i2; } }
            if (lane < 31) {
                float v2 = simS[lane + 128]; int i2 = lane + 128;
                if (v2 > v || (v2 == v && i2 < i)) { v = v2; i = i2; }
            }
            theta = wave_argmax(v, i);
        }
        int t0 = lane, t1 = lane + 64;
        int ix0 = theta + t0 - 79;
        float ya0 = (ix0 >= 0 && ix0 < 80) ? xr[ix0] : 0.0f;
        float z0 = ya0 * yr[t0] / 0.7f;
        float ya1 = 0.0f, z1 = -INFINITY;
        if (t1 < 80) {
            int ix1 = theta + t1 - 79;
            ya1 = (ix1 >= 0 && ix1 < 80) ? xr[ix1] : 0.0f;
            z1 = ya1 * yr[t1] / 0.7f;
        }
        float m = wave_max(fmaxf(z0, z1));
        float e0 = expf(z0 - m);
        float e1 = (t1 < 80) ? expf(z1 - m) : 0.0f;
        float S = wave_sum(e0 + e1);
        float v0 = ya0 * (e0 / S);
        ya[t0] = v0;
        ws[WS_YA + p * 88 + t0] = v0;
        ws[WS_YAT + t0 * 1024 + p] = v0;
        if (t1 < 80) {
            float v1 = ya1 * (e1 / S);
            ya[t1] = v1;
            ws[WS_YA + p * 88 + t1] = v1;
            ws[WS_YAT + t1 * 1024 + p] = v1;
        }
        if (lane < 8) ws[WS_YA + p * 88 + 80 + lane] = 0.0f;
        int k0 = 79 - theta + t0;
        ws[WS_XELE + base + t0] = (k0 >= 0 && k0 < 80) ? ya[k0] : 0.0f;
        if (t1 < 80) {
            int k1 = 79 - theta + t1;
            ws[WS_XELE + base + t1] = (k1 >= 0 && k1 < 80) ? ya[k1] : 0.0f;
        }
    }
}

// ---------------- k_conv: 2 positions/lane, shared readlane broadcast ----------------
__global__ __launch_bounds__(256, 2)
void k_conv(const float* __restrict__ G, const float* __restrict__ uvec,
            const float* __restrict__ yat, const float* __restrict__ bbp,
            float* __restrict__ en) {
    const int bid = blockIdx.x;       // 81 * 8
    const int s   = bid >> 3;
    const int pg  = bid & 7;
    const int c0  = 80 - s;
    const int tid = threadIdx.x;
    const int pl  = tid & 63;         // lane
    const int wv  = tid >> 6;         // 0..3 : k-quarter
    const int p0  = pg * 128 + pl;
    const int p1  = p0 + 64;

    __shared__ float e_l[512];

    const int r0 = wv * 20;
    const float* Grow = G + (c0 + r0) * GPITCH + c0;

    float acc0[20], acc1[20];
#pragma unroll
    for (int rr = 0; rr < 20; ++rr) { acc0[rr] = 0.0f; acc1[rr] = 0.0f; }

#pragma unroll 1
    for (int jt = 0; jt < 4; ++jt) {
        float y0[20], y1[20];
#pragma unroll
        for (int j = 0; j < 20; ++j) {
            y0[j] = yat[(jt * 20 + j) * 1024 + p0];
            y1[j] = yat[(jt * 20 + j) * 1024 + p1];
        }
        float g[20];
        const float* Gj = Grow + jt * 20;
#pragma unroll
        for (int rr = 0; rr < 20; ++rr) g[rr] = Gj[rr * GPITCH + pl];
#pragma unroll
        for (int j = 0; j < 20; ++j) {
            asm volatile("" : "+v"(y0[j]));
            asm volatile("" : "+v"(y1[j]));
        }
#pragma unroll
        for (int rr = 0; rr < 20; ++rr) asm volatile("" : "+v"(g[rr]));
        // j outer, rr inner; each broadcast feeds both positions' acc chains
#pragma unroll
        for (int j = 0; j < 20; ++j) {
#pragma unroll
            for (int rr = 0; rr < 20; ++rr) {
                const float gv = rl(g[rr], j);
                acc0[rr] = fmaf(gv, y0[j], acc0[rr]);
                acc1[rr] = fmaf(gv, y1[j], acc1[rr]);
            }
        }
    }

    // epilogue per position: e = sum_rr y[r0+rr] * (v_k + 2 u_k), rr ascending
    const float* up = uvec + c0 + r0;
    float e0 = 0.0f, e1 = 0.0f;
#pragma unroll
    for (int rr = 0; rr < 20; ++rr) {
        const float t = 2.0f * up[rr];
        e0 = fmaf(yat[(r0 + rr) * 1024 + p0], acc0[rr] + t, e0);
        e1 = fmaf(yat[(r0 + rr) * 1024 + p1], acc1[rr] + t, e1);
    }
    e_l[tid] = e0;
    e_l[256 + tid] = e1;
    __syncthreads();
    if (tid < 128) {
        const int q  = tid >> 6;          // 0: positions +0..63, 1: +64..127
        const int l2 = tid & 63;
        const float* el = e_l + q * 256;
        float sum = (el[l2] + el[l2 + 64]) + (el[l2 + 128] + el[l2 + 192]);
        en[(pg * 128 + q * 64 + l2) * 84 + s] = bbp[0] + sum;
    }
}

// -------- k_fuse: argmax + halved M-GEMV + loss + residuals + next-iter sel --------
__global__ __launch_bounds__(128)
void k_fuse(const float* __restrict__ yorig, const float* __restrict__ bsrc,
            float* __restrict__ ws, int it) {
    const int p = blockIdx.x, tid = threadIdx.x;
    const int lane = tid & 63;
    const int base = p * 80;

    __shared__ float ya_l[84], yr_l[80], xr_l[80], xele_l[80];
    __shared__ float xext80[80];
    __shared__ float yr2[80], xr2[80], simS[160], ya_n[88];
    __shared__ float s_ny2;
    __shared__ int s_hind;

    if (tid < 84) ya_l[tid] = ws[WS_YA + p * 88 + tid];
    if (tid < 80) {
        yr_l[tid]   = ws[WS_YRES + base + tid];
        xr_l[tid]   = ws[WS_XRES + base + tid];
        xele_l[tid] = ws[WS_XELE + base + tid];
    }
    __syncthreads();

    if (tid < 64) {
        float v = ws[WS_EN + p * 84 + lane]; int i = lane;
        if (lane < 17) {
            float v2 = ws[WS_EN + p * 84 + lane + 64]; int i2 = lane + 64;
            if (v2 > v || (v2 == v && i2 < i)) { v = v2; i = i2; }
        }
        int hind = wave_argmax(v, i);
        if (lane == 0) s_hind = hind;
    }
    __syncthreads();
    const int hd = s_hind;
    const int cb = 80 - hd;

    // xext80[t] = xext[cb+t] = bsrc[o] + d0[o] + sum_k ya[k]*Mt[(cb+k)*160+o]
    if (tid < 80) {
        const int o = cb + tid;
        const float* M = ws + WS_MT + cb * 160 + o;
        float a0 = bsrc[o] + ws[WS_D0 + o], a1 = 0.f, a2 = 0.f, a3 = 0.f;
        for (int k = 0; k < 80; k += 4) {
            a0 = fmaf(ya_l[k],     M[k * 160],       a0);
            a1 = fmaf(ya_l[k + 1], M[(k + 1) * 160], a1);
            a2 = fmaf(ya_l[k + 2], M[(k + 2) * 160], a2);
            a3 = fmaf(ya_l[k + 3], M[(k + 3) * 160], a3);
        }
        xext80[tid] = (a0 + a1) + (a2 + a3);
    }
    __syncthreads();

    if (tid < 64) {
        int t0 = lane, t1 = lane + 64;
        float sq;
        {
            float yele = xext80[t0];
            float yv = yr_l[t0];
            float keep = (yorig[base + t0] != 0.0f) ? 1.0f : 0.0f;
            float d = yele - yv;
            sq = d * d * keep;
            float ynew = yv - yele;
            float xnew = xr_l[t0] - xele_l[t0];
            yr2[t0] = ynew; xr2[t0] = xnew;
            ws[WS_YRES + base + t0] = ynew;
            ws[WS_XRES + base + t0] = xnew;
        }
        if (t1 < 80) {
            float yele = xext80[t1];
            float yv = yr_l[t1];
            float keep = (yorig[base + t1] != 0.0f) ? 1.0f : 0.0f;
            float d = yele - yv;
            sq = fmaf(d * keep, d, sq);
            float ynew = yv - yele;
            float xnew = xr_l[t1] - xele_l[t1];
            yr2[t1] = ynew; xr2[t1] = xnew;
            ws[WS_YRES + base + t1] = ynew;
            ws[WS_XRES + base + t1] = xnew;
        }
        sq = wave_sum(sq);
        if (lane == 0) atomicAdd(&ws[WS_LOSS + it], sq);
    }
    if (it == 4) return;
    __syncthreads();

    // ---- fused selector for next iteration ----
    if (tid < 64) {
        float a = yr2[lane];
        float v = a * a;
        if (lane < 16) { float u = yr2[64 + lane]; v = fmaf(u, u, v); }
        v = wave_sum(v);
        if (lane == 0) s_ny2 = v;
    }
    __syncthreads();

    for (int s = tid; s < 159; s += 128) {
        int ilo = (s - 79 > 0) ? s - 79 : 0;
        int ihi = (s < 79) ? s : 79;
        float dot = 0.0f, nx2 = 0.0f;
        for (int i = ilo; i <= ihi; ++i) {
            float xv = xr2[i];
            dot = fmaf(xv, yr2[i - s + 79], dot);
            nx2 = fmaf(xv, xv, nx2);
        }
        float denom = sqrtf(nx2) * sqrtf(s_ny2);
        simS[s] = (denom == 0.0f) ? 0.0f : dot / denom;
    }
    __syncthreads();

    if (tid < 64) {
        int theta;
        {
            float v = simS[lane]; int i = lane;
            { float v2 = simS[lane + 64]; int i2 = lane + 64;
              if (v2 > v || (v2 == v && i2 < i)) { v = v2; i = i2; } }
            if (lane < 31) {
                float v2 = simS[lane + 128]; int i2 = lane + 128;
                if (v2 > v || (v2 == v && i2 < i)) { v = v2; i = i2; }
            }
            theta = wave_argmax(v, i);
        }
        int t0 = lane, t1 = lane + 64;
        int ix0 = theta + t0 - 79;
        float ya0 = (ix0 >= 0 && ix0 < 80) ? xr2[ix0] : 0.0f;
        float z0 = ya0 * yr2[t0] / 0.7f;
        float ya1 = 0.0f, z1 = -INFINITY;
        if (t1 < 80) {
            int ix1 = theta + t1 - 79;
            ya1 = (ix1 >= 0 && ix1 < 80) ? xr2[ix1] : 0.0f;
            z1 = ya1 * yr2[t1] / 0.7f;
        }
        float m = wave_max(fmaxf(z0, z1));
        float e0 = expf(z0 - m);
        float e1 = (t1 < 80) ? expf(z1 - m) : 0.0f;
        float S = wave_sum(e0 + e1);
        float v0 = ya0 * (e0 / S);
        ya_n[t0] = v0;
        ws[WS_YA + p * 88 + t0] = v0;
        ws[WS_YAT + t0 * 1024 + p] = v0;
        if (t1 < 80) {
            float v1 = ya1 * (e1 / S);
            ya_n[t1] = v1;
            ws[WS_YA + p * 88 + t1] = v1;
            ws[WS_YAT + t1 * 1024 + p] = v1;
        }
        if (lane < 8) ws[WS_YA + p * 88 + 80 + lane] = 0.0f;
        int k0 = 79 - theta + t0;
        ws[WS_XELE + base + t0] = (k0 >= 0 && k0 < 80) ? ya_n[k0] : 0.0f;
        if (t1 < 80) {
            int k1 = 79 - theta + t1;
            ws[WS_XELE + base + t1] = (k1 >= 0 && k1 < 80) ? ya_n[k1] : 0.0f;
        }
    }
}

__global__ void k_final(const float* __restrict__ ws, float* __restrict__ out) {
    float K = ws[WS_K];
    if (K < 1.0f) K = 1.0f;
    out[0] = (ws[WS_LOSS] + ws[WS_LOSS + 1] + ws[WS_LOSS + 2] +
              ws[WS_LOSS + 3] + ws[WS_LOSS + 4]) / (K * 5.0f);
}

extern "C" void kernel_launch(void* const* d_in, const int* in_sizes, int n_in,
                              void* d_out, int out_size, void* d_ws, size_t ws_size,
                              hipStream_t stream) {
    const float* x    = (const float*)d_in[0];
    const float* y    = (const float*)d_in[1];
    const float* Wenc = (const float*)d_in[2];
    const float* benc = (const float*)d_in[3];
    const float* Wsrc = (const float*)d_in[4];
    const float* bsrc = (const float*)d_in[5];
    float* ws  = (float*)d_ws;
    float* out = (float*)d_out;

    k_init<<<320, 256, 0, stream>>>(x, y, Wenc, ws);
    k_cnt<<<320, 256, 0, stream>>>(y, ws);
    k_pre<<<161, 256, 0, stream>>>(Wenc, benc, ws);
    k_preM<<<160, 256, 0, stream>>>(Wenc, benc, Wsrc, ws);
    k_sel<<<1024, 128, 0, stream>>>(ws);
    for (int it = 0; it < 5; ++it) {
        k_conv<<<81 * 8, 256, 0, stream>>>(ws + WS_G, ws + WS_U, ws + WS_YAT,
                                           ws + WS_BB, ws + WS_EN);
        k_fuse<<<1024, 128, 0, stream>>>(y, bsrc, ws, it);
    }
    k_final<<<1, 1, 0, stream>>>(ws, out);
}

// Round 25
// 273.257 us; speedup vs baseline: 1.0705x; 1.0043x over previous
//
#include <hip/hip_runtime.h>

// Net_17532056502451 round 25: r22/r24 + batched readlanes in conv inner loop
// (all 20 rl's issued before their FMAs -> hides SGPR-write hazard).
// Per-acc summation order unchanged -> bit-identical.
//
// ws layout (floats):
#define WS_XRES   0
#define WS_YRES   81920
#define WS_WT     163840   // Wt[c*512+f] = W_enc[f*160+c]
#define WS_MT     245760   // Mt[c*160+o] = sum_f Wsrc[o,f] Wenc[f,c]  (160x160)
#define WS_D0     271360   // d0[o]
#define WS_G      327680   // G padded [160][164]
#define WS_U      353920   // u[160]
#define WS_BB     354080
#define WS_K      354081
#define WS_LOSS   354082   // 5 raw sq-sums (atomic)
#define WS_YA     354088   // [1024][88]   (fuse-local layout)
#define WS_XELE   444200   // [1024][80]
#define WS_EN     526120   // [1024][84]
#define WS_YAT    612160   // [80][1024]   (conv layout, transposed)

#define GPITCH 164

__device__ __forceinline__ float rl(float v, int l) {
    return __int_as_float(__builtin_amdgcn_readlane(__float_as_int(v), l));
}

__global__ void k_init(const float* __restrict__ x, const float* __restrict__ y,
                       const float* __restrict__ Wenc, float* __restrict__ ws) {
    int i = blockIdx.x * 256 + threadIdx.x;   // covers 81920
    ws[WS_XRES + i] = x[i];
    ws[WS_YRES + i] = y[i];
    int f = i / 160, c = i - f * 160;
    ws[WS_WT + c * 512 + f] = Wenc[i];
    if (i == 0) {
        ws[WS_K] = 0.0f;
        for (int t = 0; t < 5; ++t) ws[WS_LOSS + t] = 0.0f;
    }
}

__device__ __forceinline__ float wave_sum(float v) {
    for (int d = 32; d > 0; d >>= 1) v += __shfl_down(v, d);
    return __shfl(v, 0);
}
__device__ __forceinline__ float wave_max(float v) {
    for (int d = 32; d > 0; d >>= 1) v = fmaxf(v, __shfl_down(v, d));
    return __shfl(v, 0);
}
__device__ __forceinline__ int wave_argmax(float v, int i) {
    for (int d = 32; d > 0; d >>= 1) {
        float v2 = __shfl_down(v, d);
        int   i2 = __shfl_down(i, d);
        if (v2 > v || (v2 == v && i2 < i)) { v = v2; i = i2; }
    }
    return __shfl(i, 0);
}

__global__ __launch_bounds__(256)
void k_cnt(const float* __restrict__ y, float* __restrict__ ws) {
    __shared__ int red[256];
    int tid = threadIdx.x;
    int i = blockIdx.x * 256 + tid;
    red[tid] = (y[i] != 0.0f) ? 1 : 0;
    __syncthreads();
    for (int s = 128; s > 0; s >>= 1) {
        if (tid < s) red[tid] += red[tid + s];
        __syncthreads();
    }
    if (tid == 0) atomicAdd(&ws[WS_K], (float)red[0]);
}

// G rows (b<160) / u+bb (b==160): per-thread column, coalesced Wenc reads.
__global__ __launch_bounds__(256)
void k_pre(const float* __restrict__ Wenc, const float* __restrict__ benc,
           float* __restrict__ ws) {
    const int b = blockIdx.x, tid = threadIdx.x;
    __shared__ float wr[512];
    if (b < 160) {
        wr[tid] = ws[WS_WT + b * 512 + tid];
        wr[tid + 256] = ws[WS_WT + b * 512 + 256 + tid];
        __syncthreads();
        if (tid < 160) {
            const float* Wc = Wenc + tid;
            float a0 = 0.f, a1 = 0.f, a2 = 0.f, a3 = 0.f;
            for (int f = 0; f < 512; f += 4) {
                a0 = fmaf(wr[f],     Wc[f * 160],       a0);
                a1 = fmaf(wr[f + 1], Wc[(f + 1) * 160], a1);
                a2 = fmaf(wr[f + 2], Wc[(f + 2) * 160], a2);
                a3 = fmaf(wr[f + 3], Wc[(f + 3) * 160], a3);
            }
            ws[WS_G + b * GPITCH + tid] = (a0 + a1) + (a2 + a3);
        }
    } else {
        wr[tid] = benc[tid];
        wr[tid + 256] = benc[tid + 256];
        __syncthreads();
        if (tid < 160) {
            const float* Wc = Wenc + tid;
            float a0 = 0.f, a1 = 0.f, a2 = 0.f, a3 = 0.f;
            for (int f = 0; f < 512; f += 4) {
                a0 = fmaf(wr[f],     Wc[f * 160],       a0);
                a1 = fmaf(wr[f + 1], Wc[(f + 1) * 160], a1);
                a2 = fmaf(wr[f + 2], Wc[(f + 2) * 160], a2);
                a3 = fmaf(wr[f + 3], Wc[(f + 3) * 160], a3);
            }
            ws[WS_U + tid] = (a0 + a1) + (a2 + a3);
        }
        if (tid < 64) {
            float a = 0.0f;
#pragma unroll
            for (int jj = 0; jj < 8; ++jj) {
                float bv = wr[tid + 64 * jj];
                a = fmaf(bv, bv, a);
            }
            a = wave_sum(a);
            if (tid == 0) ws[WS_BB] = a;
        }
    }
}

// Mt[c][o] = sum_f Wsrc[o,f] Wenc[f,c]; d0[o] = sum_f Wsrc[o,f] benc[f]
__global__ __launch_bounds__(256)
void k_preM(const float* __restrict__ Wenc, const float* __restrict__ benc,
            const float* __restrict__ Wsrc, float* __restrict__ ws) {
    const int o = blockIdx.x, tid = threadIdx.x;
    __shared__ float wr[512];
    wr[tid] = Wsrc[o * 512 + tid];
    wr[tid + 256] = Wsrc[o * 512 + 256 + tid];
    __syncthreads();
    if (tid < 160) {
        const float* Wc = Wenc + tid;
        float a0 = 0.f, a1 = 0.f, a2 = 0.f, a3 = 0.f;
        for (int f = 0; f < 512; f += 4) {
            a0 = fmaf(wr[f],     Wc[f * 160],       a0);
            a1 = fmaf(wr[f + 1], Wc[(f + 1) * 160], a1);
            a2 = fmaf(wr[f + 2], Wc[(f + 2) * 160], a2);
            a3 = fmaf(wr[f + 3], Wc[(f + 3) * 160], a3);
        }
        ws[WS_MT + tid * 160 + o] = (a0 + a1) + (a2 + a3);
    }
    if (tid < 64) {
        float a = 0.0f;
#pragma unroll
        for (int jj = 0; jj < 8; ++jj)
            a = fmaf(wr[tid + 64 * jj], benc[tid + 64 * jj], a);
        a = wave_sum(a);
        if (tid == 0) ws[WS_D0 + o] = a;
    }
}

// ---------------- k_sel: initial selector + softmax per position ----------------
__global__ __launch_bounds__(128)
void k_sel(float* __restrict__ ws) {
    const int p = blockIdx.x, tid = threadIdx.x, lane = tid & 63;
    const int base = p * 80;
    __shared__ float xr[80], yr[80], simS[160], ya[88];
    __shared__ float s_ny2;

    if (tid < 80) { xr[tid] = ws[WS_XRES + base + tid]; yr[tid] = ws[WS_YRES + base + tid]; }
    __syncthreads();

    if (tid < 64) {
        float a = yr[lane];
        float v = a * a;
        if (lane < 16) { float u = yr[64 + lane]; v = fmaf(u, u, v); }
        v = wave_sum(v);
        if (lane == 0) s_ny2 = v;
    }
    __syncthreads();

    for (int s = tid; s < 159; s += 128) {
        int ilo = (s - 79 > 0) ? s - 79 : 0;
        int ihi = (s < 79) ? s : 79;
        float dot = 0.0f, nx2 = 0.0f;
        for (int i = ilo; i <= ihi; ++i) {
            float xv = xr[i];
            dot = fmaf(xv, yr[i - s + 79], dot);
            nx2 = fmaf(xv, xv, nx2);
        }
        float denom = sqrtf(nx2) * sqrtf(s_ny2);
        simS[s] = (denom == 0.0f) ? 0.0f : dot / denom;
    }
    __syncthreads();

    if (tid < 64) {
        int theta;
        {
            float v = simS[lane]; int i = lane;
            { float v2 = simS[lane + 64]; int i2 = lane + 64;
              if (v2 > v || (v2 == v && i2 < i)) { v = v2; i = i2; } }
            if (lane < 31) {
                float v2 = simS[lane + 128]; int i2 = lane + 128;
                if (v2 > v || (v2 == v && i2 < i)) { v = v2; i = i2; }
            }
            theta = wave_argmax(v, i);
        }
        int t0 = lane, t1 = lane + 64;
        int ix0 = theta + t0 - 79;
        float ya0 = (ix0 >= 0 && ix0 < 80) ? xr[ix0] : 0.0f;
        float z0 = ya0 * yr[t0] / 0.7f;
        float ya1 = 0.0f, z1 = -INFINITY;
        if (t1 < 80) {
            int ix1 = theta + t1 - 79;
            ya1 = (ix1 >= 0 && ix1 < 80) ? xr[ix1] : 0.0f;
            z1 = ya1 * yr[t1] / 0.7f;
        }
        float m = wave_max(fmaxf(z0, z1));
        float e0 = expf(z0 - m);
        float e1 = (t1 < 80) ? expf(z1 - m) : 0.0f;
        float S = wave_sum(e0 + e1);
        float v0 = ya0 * (e0 / S);
        ya[t0] = v0;
        ws[WS_YA + p * 88 + t0] = v0;
        ws[WS_YAT + t0 * 1024 + p] = v0;
        if (t1 < 80) {
            float v1 = ya1 * (e1 / S);
            ya[t1] = v1;
            ws[WS_YA + p * 88 + t1] = v1;
            ws[WS_YAT + t1 * 1024 + p] = v1;
        }
        if (lane < 8) ws[WS_YA + p * 88 + 80 + lane] = 0.0f;
        int k0 = 79 - theta + t0;
        ws[WS_XELE + base + t0] = (k0 >= 0 && k0 < 80) ? ya[k0] : 0.0f;
        if (t1 < 80) {
            int k1 = 79 - theta + t1;
            ws[WS_XELE + base + t1] = (k1 >= 0 && k1 < 80) ? ya[k1] : 0.0f;
        }
    }
}

// ---------------- k_conv: 2 positions/lane, batched readlane broadcasts ----------------
__global__ __launch_bounds__(256, 2)
void k_conv(const float* __restrict__ G, const float* __restrict__ uvec,
            const float* __restrict__ yat, const float* __restrict__ bbp,
            float* __restrict__ en) {
    const int bid = blockIdx.x;       // 81 * 8
    const int s   = bid >> 3;
    const int pg  = bid & 7;
    const int c0  = 80 - s;
    const int tid = threadIdx.x;
    const int pl  = tid & 63;         // lane
    const int wv  = tid >> 6;         // 0..3 : k-quarter
    const int p0  = pg * 128 + pl;
    const int p1  = p0 + 64;

    __shared__ float e_l[512];

    const int r0 = wv * 20;
    const float* Grow = G + (c0 + r0) * GPITCH + c0;

    float acc0[20], acc1[20];
#pragma unroll
    for (int rr = 0; rr < 20; ++rr) { acc0[rr] = 0.0f; acc1[rr] = 0.0f; }

#pragma unroll 1
    for (int jt = 0; jt < 4; ++jt) {
        float y0[20], y1[20];
#pragma unroll
        for (int j = 0; j < 20; ++j) {
            y0[j] = yat[(jt * 20 + j) * 1024 + p0];
            y1[j] = yat[(jt * 20 + j) * 1024 + p1];
        }
        float g[20];
        const float* Gj = Grow + jt * 20;
#pragma unroll
        for (int rr = 0; rr < 20; ++rr) g[rr] = Gj[rr * GPITCH + pl];
#pragma unroll
        for (int j = 0; j < 20; ++j) {
            asm volatile("" : "+v"(y0[j]));
            asm volatile("" : "+v"(y1[j]));
        }
#pragma unroll
        for (int rr = 0; rr < 20; ++rr) asm volatile("" : "+v"(g[rr]));
        // j outer; batch ALL 20 readlanes first, then the 40 FMAs
        // (hides the v_readlane->SGPR-read hazard behind younger readlanes).
#pragma unroll
        for (int j = 0; j < 20; ++j) {
            float gv[20];
#pragma unroll
            for (int rr = 0; rr < 20; ++rr) gv[rr] = rl(g[rr], j);
#pragma unroll
            for (int rr = 0; rr < 20; ++rr) {
                acc0[rr] = fmaf(gv[rr], y0[j], acc0[rr]);
                acc1[rr] = fmaf(gv[rr], y1[j], acc1[rr]);
            }
        }
    }

    // epilogue per position: e = sum_rr y[r0+rr] * (v_k + 2 u_k), rr ascending
    const float* up = uvec + c0 + r0;
    float e0 = 0.0f, e1 = 0.0f;
#pragma unroll
    for (int rr = 0; rr < 20; ++rr) {
        const float t = 2.0f * up[rr];
        e0 = fmaf(yat[(r0 + rr) * 1024 + p0], acc0[rr] + t, e0);
        e1 = fmaf(yat[(r0 + rr) * 1024 + p1], acc1[rr] + t, e1);
    }
    e_l[tid] = e0;
    e_l[256 + tid] = e1;
    __syncthreads();
    if (tid < 128) {
        const int q  = tid >> 6;          // 0: positions +0..63, 1: +64..127
        const int l2 = tid & 63;
        const float* el = e_l + q * 256;
        float sum = (el[l2] + el[l2 + 64]) + (el[l2 + 128] + el[l2 + 192]);
        en[(pg * 128 + q * 64 + l2) * 84 + s] = bbp[0] + sum;
    }
}

// -------- k_fuse: argmax + halved M-GEMV + loss + residuals + next-iter sel --------
__global__ __launch_bounds__(128)
void k_fuse(const float* __restrict__ yorig, const float* __restrict__ bsrc,
            float* __restrict__ ws, int it) {
    const int p = blockIdx.x, tid = threadIdx.x;
    const int lane = tid & 63;
    const int base = p * 80;

    __shared__ float ya_l[84], yr_l[80], xr_l[80], xele_l[80];
    __shared__ float xext80[80];
    __shared__ float yr2[80], xr2[80], simS[160], ya_n[88];
    __shared__ float s_ny2;
    __shared__ int s_hind;

    if (tid < 84) ya_l[tid] = ws[WS_YA + p * 88 + tid];
    if (tid < 80) {
        yr_l[tid]   = ws[WS_YRES + base + tid];
        xr_l[tid]   = ws[WS_XRES + base + tid];
        xele_l[tid] = ws[WS_XELE + base + tid];
    }
    __syncthreads();

    if (tid < 64) {
        float v = ws[WS_EN + p * 84 + lane]; int i = lane;
        if (lane < 17) {
            float v2 = ws[WS_EN + p * 84 + lane + 64]; int i2 = lane + 64;
            if (v2 > v || (v2 == v && i2 < i)) { v = v2; i = i2; }
        }
        int hind = wave_argmax(v, i);
        if (lane == 0) s_hind = hind;
    }
    __syncthreads();
    const int hd = s_hind;
    const int cb = 80 - hd;

    // xext80[t] = xext[cb+t] = bsrc[o] + d0[o] + sum_k ya[k]*Mt[(cb+k)*160+o]
    if (tid < 80) {
        const int o = cb + tid;
        const float* M = ws + WS_MT + cb * 160 + o;
        float a0 = bsrc[o] + ws[WS_D0 + o], a1 = 0.f, a2 = 0.f, a3 = 0.f;
        for (int k = 0; k < 80; k += 4) {
            a0 = fmaf(ya_l[k],     M[k * 160],       a0);
            a1 = fmaf(ya_l[k + 1], M[(k + 1) * 160], a1);
            a2 = fmaf(ya_l[k + 2], M[(k + 2) * 160], a2);
            a3 = fmaf(ya_l[k + 3], M[(k + 3) * 160], a3);
        }
        xext80[tid] = (a0 + a1) + (a2 + a3);
    }
    __syncthreads();

    if (tid < 64) {
        int t0 = lane, t1 = lane + 64;
        float sq;
        {
            float yele = xext80[t0];
            float yv = yr_l[t0];
            float keep = (yorig[base + t0] != 0.0f) ? 1.0f : 0.0f;
            float d = yele - yv;
            sq = d * d * keep;
            float ynew = yv - yele;
            float xnew = xr_l[t0] - xele_l[t0];
            yr2[t0] = ynew; xr2[t0] = xnew;
            ws[WS_YRES + base + t0] = ynew;
            ws[WS_XRES + base + t0] = xnew;
        }
        if (t1 < 80) {
            float yele = xext80[t1];
            float yv = yr_l[t1];
            float keep = (yorig[base + t1] != 0.0f) ? 1.0f : 0.0f;
            float d = yele - yv;
            sq = fmaf(d * keep, d, sq);
            float ynew = yv - yele;
            float xnew = xr_l[t1] - xele_l[t1];
            yr2[t1] = ynew; xr2[t1] = xnew;
            ws[WS_YRES + base + t1] = ynew;
            ws[WS_XRES + base + t1] = xnew;
        }
        sq = wave_sum(sq);
        if (lane == 0) atomicAdd(&ws[WS_LOSS + it], sq);
    }
    if (it == 4) return;
    __syncthreads();

    // ---- fused selector for next iteration ----
    if (tid < 64) {
        float a = yr2[lane];
        float v = a * a;
        if (lane < 16) { float u = yr2[64 + lane]; v = fmaf(u, u, v); }
        v = wave_sum(v);
        if (lane == 0) s_ny2 = v;
    }
    __syncthreads();

    for (int s = tid; s < 159; s += 128) {
        int ilo = (s - 79 > 0) ? s - 79 : 0;
        int ihi = (s < 79) ? s : 79;
        float dot = 0.0f, nx2 = 0.0f;
        for (int i = ilo; i <= ihi; ++i) {
            float xv = xr2[i];
            dot = fmaf(xv, yr2[i - s + 79], dot);
            nx2 = fmaf(xv, xv, nx2);
        }
        float denom = sqrtf(nx2) * sqrtf(s_ny2);
        simS[s] = (denom == 0.0f) ? 0.0f : dot / denom;
    }
    __syncthreads();

    if (tid < 64) {
        int theta;
        {
            float v = simS[lane]; int i = lane;
            { float v2 = simS[lane + 64]; int i2 = lane + 64;
              if (v2 > v || (v2 == v && i2 < i)) { v = v2; i = i2; } }
            if (lane < 31) {
                float v2 = simS[lane + 128]; int i2 = lane + 128;
                if (v2 > v || (v2 == v && i2 < i)) { v = v2; i = i2; }
            }
            theta = wave_argmax(v, i);
        }
        int t0 = lane, t1 = lane + 64;
        int ix0 = theta + t0 - 79;
        float ya0 = (ix0 >= 0 && ix0 < 80) ? xr2[ix0] : 0.0f;
        float z0 = ya0 * yr2[t0] / 0.7f;
        float ya1 = 0.0f, z1 = -INFINITY;
        if (t1 < 80) {
            int ix1 = theta + t1 - 79;
            ya1 = (ix1 >= 0 && ix1 < 80) ? xr2[ix1] : 0.0f;
            z1 = ya1 * yr2[t1] / 0.7f;
        }
        float m = wave_max(fmaxf(z0, z1));
        float e0 = expf(z0 - m);
        float e1 = (t1 < 80) ? expf(z1 - m) : 0.0f;
        float S = wave_sum(e0 + e1);
        float v0 = ya0 * (e0 / S);
        ya_n[t0] = v0;
        ws[WS_YA + p * 88 + t0] = v0;
        ws[WS_YAT + t0 * 1024 + p] = v0;
        if (t1 < 80) {
            float v1 = ya1 * (e1 / S);
            ya_n[t1] = v1;
            ws[WS_YA + p * 88 + t1] = v1;
            ws[WS_YAT + t1 * 1024 + p] = v1;
        }
        if (lane < 8) ws[WS_YA + p * 88 + 80 + lane] = 0.0f;
        int k0 = 79 - theta + t0;
        ws[WS_XELE + base + t0] = (k0 >= 0 && k0 < 80) ? ya_n[k0] : 0.0f;
        if (t1 < 80) {
            int k1 = 79 - theta + t1;
            ws[WS_XELE + base + t1] = (k1 >= 0 && k1 < 80) ? ya_n[k1] : 0.0f;
        }
    }
}

__global__ void k_final(const float* __restrict__ ws, float* __restrict__ out) {
    float K = ws[WS_K];
    if (K < 1.0f) K = 1.0f;
    out[0] = (ws[WS_LOSS] + ws[WS_LOSS + 1] + ws[WS_LOSS + 2] +
              ws[WS_LOSS + 3] + ws[WS_LOSS + 4]) / (K * 5.0f);
}

extern "C" void kernel_launch(void* const* d_in, const int* in_sizes, int n_in,
                              void* d_out, int out_size, void* d_ws, size_t ws_size,
                              hipStream_t stream) {
    const float* x    = (const float*)d_in[0];
    const float* y    = (const float*)d_in[1];
    const float* Wenc = (const float*)d_in[2];
    const float* benc = (const float*)d_in[3];
    const float* Wsrc = (const float*)d_in[4];
    const float* bsrc = (const float*)d_in[5];
    float* ws  = (float*)d_ws;
    float* out = (float*)d_out;

    k_init<<<320, 256, 0, stream>>>(x, y, Wenc, ws);
    k_cnt<<<320, 256, 0, stream>>>(y, ws);
    k_pre<<<161, 256, 0, stream>>>(Wenc, benc, ws);
    k_preM<<<160, 256, 0, stream>>>(Wenc, benc, Wsrc, ws);
    k_sel<<<1024, 128, 0, stream>>>(ws);
    for (int it = 0; it < 5; ++it) {
        k_conv<<<81 * 8, 256, 0, stream>>>(ws + WS_G, ws + WS_U, ws + WS_YAT,
                                           ws + WS_BB, ws + WS_EN);
        k_fuse<<<1024, 128, 0, stream>>>(y, bsrc, ws, it);
    }
    k_final<<<1, 1, 0, stream>>>(ws, out);
}